// Round 2
// baseline (2361.753 us; speedup 1.0000x reference)
//
#include <hip/hip_runtime.h>
#include <cstdint>
#include <cstddef>

typedef unsigned short u16;
typedef __bf16 bf16x8 __attribute__((ext_vector_type(8)));
typedef float f32x4 __attribute__((ext_vector_type(4)));

#define B_ 2
#define S_ 2048
#define D_ 1024
#define H_ 16
#define G_ 4
#define HD_ 64
#define E_ 8
#define F_ 4096
#define T_ 4096

__device__ __forceinline__ u16 f2b(float f) {
  unsigned u = __float_as_uint(f);
  return (u16)((u + 0x7fffu + ((u >> 16) & 1u)) >> 16);
}

__device__ __forceinline__ float gelu_t(float x) {
  // tanh-approx gelu (jax.nn.gelu approximate=True)
  float u = 0.7978845608028654f * (x + 0.044715f * x * x * x);
  float t = 1.f - 2.f / (__expf(2.f * u) + 1.f);
  return 0.5f * x * (1.f + t);
}

__device__ __forceinline__ void gload16(const void* g, void* l) {
  __builtin_amdgcn_global_load_lds((__attribute__((address_space(1))) void*)g,
                                   (__attribute__((address_space(3))) void*)l, 16, 0, 0);
}

// ---------------- small utility kernels ----------------

__global__ void k_zero(int* cnt) {
  if (threadIdx.x < E_) cnt[threadIdx.x] = 0;
}

// batched transpose + f32->bf16: dst[z][C][R] = bf16(src[z][R][C])
__global__ __launch_bounds__(256) void k_transpose(const float* __restrict__ src,
                                                   u16* __restrict__ dst, int R, int C) {
  __shared__ u16 tile[32][33];
  int c0 = blockIdx.x * 32, r0 = blockIdx.y * 32;
  size_t zo = (size_t)blockIdx.z * (size_t)R * (size_t)C;
  int tx = threadIdx.x, ty = threadIdx.y;
  #pragma unroll
  for (int i = ty; i < 32; i += 8) {
    int r = r0 + i, cc = c0 + tx;
    float v = (r < R && cc < C) ? src[zo + (size_t)r * C + cc] : 0.f;
    tile[i][tx] = f2b(v);
  }
  __syncthreads();
  #pragma unroll
  for (int i = ty; i < 32; i += 8) {
    int cc = c0 + i, r = r0 + tx;
    if (cc < C && r < R) dst[zo + (size_t)cc * R + r] = tile[tx][i];
  }
}

// LayerNorm over D=1024, one block per token; optional bf16 copy out
__global__ __launch_bounds__(256) void k_ln(const float* __restrict__ x,
                                            const float* __restrict__ sc,
                                            const float* __restrict__ bi,
                                            float* __restrict__ of,
                                            u16* __restrict__ ob) {
  int t = blockIdx.x, tid = threadIdx.x;
  const float* row = x + (size_t)t * D_;
  float4 v = *(const float4*)&row[tid * 4];
  float s = v.x + v.y + v.z + v.w;
  float ss = v.x * v.x + v.y * v.y + v.z * v.z + v.w * v.w;
  #pragma unroll
  for (int off = 32; off > 0; off >>= 1) {
    s += __shfl_xor(s, off);
    ss += __shfl_xor(ss, off);
  }
  __shared__ float red[8];
  if ((tid & 63) == 0) { red[(tid >> 6) * 2] = s; red[(tid >> 6) * 2 + 1] = ss; }
  __syncthreads();
  float S = red[0] + red[2] + red[4] + red[6];
  float SS = red[1] + red[3] + red[5] + red[7];
  float mu = S * (1.f / D_);
  float var = SS * (1.f / D_) - mu * mu;
  float rs = rsqrtf(var + 1e-6f);
  float4 scv = *(const float4*)&sc[tid * 4];
  float4 biv = *(const float4*)&bi[tid * 4];
  float4 o;
  o.x = (v.x - mu) * rs * scv.x + biv.x;
  o.y = (v.y - mu) * rs * scv.y + biv.y;
  o.z = (v.z - mu) * rs * scv.z + biv.z;
  o.w = (v.w - mu) * rs * scv.w + biv.w;
  *(float4*)&of[(size_t)t * D_ + tid * 4] = o;
  if (ob) {
    ushort4 u;
    u.x = f2b(o.x); u.y = f2b(o.y); u.z = f2b(o.z); u.w = f2b(o.w);
    *(ushort4*)&ob[(size_t)t * D_ + tid * 4] = u;
  }
}

// ---------------- fp32 vector GEMM: C[M,N] = A[M,K] @ B[K,N] + bias (+xres) ----------------
// 64x64 tile per 256-thread block, BK=16, 4x4 per thread.
__global__ __launch_bounds__(256) void k_gemm_f32(const float* __restrict__ A,
                                                  const float* __restrict__ Bm,
                                                  const float* __restrict__ bias,
                                                  const float* __restrict__ xres,
                                                  float* __restrict__ C,
                                                  int M, int N, int K) {
  __shared__ __align__(16) float As[16 * 64];
  __shared__ __align__(16) float Bs[16 * 64];
  int tid = threadIdx.x;
  int m0 = blockIdx.x * 64, n0 = blockIdx.y * 64;
  int qt = tid >> 4, nt = tid & 15;
  int ar = tid >> 2, ak = (tid & 3) * 4;   // A stage: row ar, k-chunk ak
  int bk = tid >> 4, bn = (tid & 15) * 4;  // B stage: row bk, n-chunk bn
  float acc[4][4];
  #pragma unroll
  for (int i = 0; i < 4; ++i)
    #pragma unroll
    for (int j = 0; j < 4; ++j) acc[i][j] = 0.f;

  for (int k0 = 0; k0 < K; k0 += 16) {
    float4 av = *(const float4*)&A[(size_t)(m0 + ar) * K + k0 + ak];
    float4 bv = *(const float4*)&Bm[(size_t)(k0 + bk) * N + n0 + bn];
    __syncthreads();
    As[(ak + 0) * 64 + ar] = av.x;
    As[(ak + 1) * 64 + ar] = av.y;
    As[(ak + 2) * 64 + ar] = av.z;
    As[(ak + 3) * 64 + ar] = av.w;
    *(float4*)&Bs[bk * 64 + bn] = bv;
    __syncthreads();
    #pragma unroll
    for (int kk = 0; kk < 16; ++kk) {
      float4 a4 = *(const float4*)&As[kk * 64 + qt * 4];
      float4 b4 = *(const float4*)&Bs[kk * 64 + nt * 4];
      float av_[4] = {a4.x, a4.y, a4.z, a4.w};
      float bv_[4] = {b4.x, b4.y, b4.z, b4.w};
      #pragma unroll
      for (int i = 0; i < 4; ++i)
        #pragma unroll
        for (int j = 0; j < 4; ++j) acc[i][j] = fmaf(av_[i], bv_[j], acc[i][j]);
    }
  }
  float4 bv4 = *(const float4*)&bias[n0 + nt * 4];
  #pragma unroll
  for (int i = 0; i < 4; ++i) {
    int gm = m0 + qt * 4 + i;
    size_t base = (size_t)gm * N + n0 + nt * 4;
    float4 r;
    r.x = acc[i][0] + bv4.x;
    r.y = acc[i][1] + bv4.y;
    r.z = acc[i][2] + bv4.z;
    r.w = acc[i][3] + bv4.w;
    if (xres) {
      float4 xr = *(const float4*)&xres[base];
      r.x += xr.x; r.y += xr.y; r.z += xr.z; r.w += xr.w;
    }
    *(float4*)&C[base] = r;
  }
}

// ---------------- fp32 flash attention with session-delta decay ----------------
// block: 256 threads, one (b,h,64-query tile). 64-key steps, online softmax.
__global__ __launch_bounds__(256) void k_attn(const float* __restrict__ q,
                                              const float* __restrict__ k,
                                              const float* __restrict__ v,
                                              const float* __restrict__ sd,
                                              const float* __restrict__ td,
                                              float* __restrict__ o) {
  __shared__ __align__(16) float Qst[64 * 64];   // Q^T [hd][q]
  __shared__ __align__(16) float KP[64 * 68];    // K^T [hd][s] (stride 64) then P [q][s] (stride 68)
  __shared__ __align__(16) float Vs[64 * 64];    // V [s][hd]
  int tid = threadIdx.x;
  int q0 = blockIdx.x * 64;
  int h = blockIdx.y, b = blockIdx.z;
  int g = h >> 2;  // H/G = 4
  int qt = tid >> 4, nt = tid & 15;
  int r = tid >> 2, cb = (tid & 3) * 4;
  // stage full 64x64 Q tile: 4 chunks of 16 columns per thread
  #pragma unroll
  for (int cc = 0; cc < 4; ++cc) {
    int c = cb + cc * 16;
    float4 qv = *(const float4*)&q[((size_t)(b * S_) + q0 + r) * (H_ * HD_) + h * HD_ + c];
    Qst[(c + 0) * 64 + r] = qv.x;
    Qst[(c + 1) * 64 + r] = qv.y;
    Qst[(c + 2) * 64 + r] = qv.z;
    Qst[(c + 3) * 64 + r] = qv.w;
  }
  float sp = log1pf(expf(td[h]));  // softplus(time_decay[h])
  float dq[4];
  #pragma unroll
  for (int i = 0; i < 4; ++i) dq[i] = sd[b * S_ + q0 + qt * 4 + i];
  float mr[4], lr[4], oa[4][4];
  #pragma unroll
  for (int i = 0; i < 4; ++i) {
    mr[i] = -3.0e38f; lr[i] = 0.f;
    #pragma unroll
    for (int j = 0; j < 4; ++j) oa[i][j] = 0.f;
  }

  for (int s0 = 0; s0 < S_; s0 += 64) {
    float4 kvr[4], vvr[4];
    #pragma unroll
    for (int cc = 0; cc < 4; ++cc) {
      int c = cb + cc * 16;
      kvr[cc] = *(const float4*)&k[((size_t)(b * S_) + s0 + r) * (G_ * HD_) + g * HD_ + c];
      vvr[cc] = *(const float4*)&v[((size_t)(b * S_) + s0 + r) * (G_ * HD_) + g * HD_ + c];
    }
    float dsv[4];
    #pragma unroll
    for (int j = 0; j < 4; ++j) dsv[j] = sd[b * S_ + s0 + nt * 4 + j];
    __syncthreads();  // prior PV reads done before overwriting KP/Vs
    #pragma unroll
    for (int cc = 0; cc < 4; ++cc) {
      int c = cb + cc * 16;
      KP[(c + 0) * 64 + r] = kvr[cc].x;
      KP[(c + 1) * 64 + r] = kvr[cc].y;
      KP[(c + 2) * 64 + r] = kvr[cc].z;
      KP[(c + 3) * 64 + r] = kvr[cc].w;
      *(float4*)&Vs[r * 64 + c] = vvr[cc];
    }
    __syncthreads();
    // scores 4q x 4s per thread
    float sc[4][4];
    #pragma unroll
    for (int i = 0; i < 4; ++i)
      #pragma unroll
      for (int j = 0; j < 4; ++j) sc[i][j] = 0.f;
    #pragma unroll 16
    for (int hd = 0; hd < 64; ++hd) {
      float4 a4 = *(const float4*)&Qst[hd * 64 + qt * 4];
      float4 b4 = *(const float4*)&KP[hd * 64 + nt * 4];
      float av_[4] = {a4.x, a4.y, a4.z, a4.w};
      float bv_[4] = {b4.x, b4.y, b4.z, b4.w};
      #pragma unroll
      for (int i = 0; i < 4; ++i)
        #pragma unroll
        for (int j = 0; j < 4; ++j) sc[i][j] = fmaf(av_[i], bv_[j], sc[i][j]);
    }
    #pragma unroll
    for (int i = 0; i < 4; ++i)
      #pragma unroll
      for (int j = 0; j < 4; ++j)
        sc[i][j] = sc[i][j] * 0.125f - sp * fabsf(dq[i] - dsv[j]);
    // online softmax
    float mx[4];
    #pragma unroll
    for (int i = 0; i < 4; ++i)
      mx[i] = fmaxf(fmaxf(sc[i][0], sc[i][1]), fmaxf(sc[i][2], sc[i][3]));
    #pragma unroll
    for (int d = 1; d < 16; d <<= 1)
      #pragma unroll
      for (int i = 0; i < 4; ++i) mx[i] = fmaxf(mx[i], __shfl_xor(mx[i], d));
    float al[4], p[4][4], rsum[4];
    #pragma unroll
    for (int i = 0; i < 4; ++i) {
      float mn = fmaxf(mr[i], mx[i]);
      al[i] = __expf(mr[i] - mn);
      mr[i] = mn;
      rsum[i] = 0.f;
      #pragma unroll
      for (int j = 0; j < 4; ++j) { p[i][j] = __expf(sc[i][j] - mn); rsum[i] += p[i][j]; }
    }
    #pragma unroll
    for (int d = 1; d < 16; d <<= 1)
      #pragma unroll
      for (int i = 0; i < 4; ++i) rsum[i] += __shfl_xor(rsum[i], d);
    #pragma unroll
    for (int i = 0; i < 4; ++i) {
      lr[i] = lr[i] * al[i] + rsum[i];
      #pragma unroll
      for (int j = 0; j < 4; ++j) oa[i][j] *= al[i];
    }
    __syncthreads();  // everyone done reading K^T before writing P over it
    #pragma unroll
    for (int i = 0; i < 4; ++i) {
      float4 pv = make_float4(p[i][0], p[i][1], p[i][2], p[i][3]);
      *(float4*)&KP[(qt * 4 + i) * 68 + nt * 4] = pv;
    }
    __syncthreads();
    // PV: oa[4q][4hd] += P[q][s] * V[s][hd]
    #pragma unroll 16
    for (int s = 0; s < 64; ++s) {
      float4 b4 = *(const float4*)&Vs[s * 64 + nt * 4];
      float a0 = KP[(qt * 4 + 0) * 68 + s];
      float a1 = KP[(qt * 4 + 1) * 68 + s];
      float a2 = KP[(qt * 4 + 2) * 68 + s];
      float a3 = KP[(qt * 4 + 3) * 68 + s];
      oa[0][0] = fmaf(a0, b4.x, oa[0][0]); oa[0][1] = fmaf(a0, b4.y, oa[0][1]);
      oa[0][2] = fmaf(a0, b4.z, oa[0][2]); oa[0][3] = fmaf(a0, b4.w, oa[0][3]);
      oa[1][0] = fmaf(a1, b4.x, oa[1][0]); oa[1][1] = fmaf(a1, b4.y, oa[1][1]);
      oa[1][2] = fmaf(a1, b4.z, oa[1][2]); oa[1][3] = fmaf(a1, b4.w, oa[1][3]);
      oa[2][0] = fmaf(a2, b4.x, oa[2][0]); oa[2][1] = fmaf(a2, b4.y, oa[2][1]);
      oa[2][2] = fmaf(a2, b4.z, oa[2][2]); oa[2][3] = fmaf(a2, b4.w, oa[2][3]);
      oa[3][0] = fmaf(a3, b4.x, oa[3][0]); oa[3][1] = fmaf(a3, b4.y, oa[3][1]);
      oa[3][2] = fmaf(a3, b4.z, oa[3][2]); oa[3][3] = fmaf(a3, b4.w, oa[3][3]);
    }
  }
  #pragma unroll
  for (int i = 0; i < 4; ++i) {
    float inv = 1.f / lr[i];
    float4 r4 = make_float4(oa[i][0] * inv, oa[i][1] * inv, oa[i][2] * inv, oa[i][3] * inv);
    *(float4*)&o[((size_t)(b * S_) + q0 + qt * 4 + i) * (H_ * HD_) + h * HD_ + nt * 4] = r4;
  }
}

// ---------------- router: fp32 logits, top-2, expert bucketing ----------------
__global__ __launch_bounds__(256) void k_router(const float* __restrict__ xn2,
                                                const float* __restrict__ rw,
                                                const float* __restrict__ rb,
                                                int* __restrict__ eidx, int* __restrict__ epos,
                                                float* __restrict__ ew, int* __restrict__ cnt,
                                                int* __restrict__ list) {
  int t = blockIdx.x * 4 + (threadIdx.x >> 6);
  int l = threadIdx.x & 63;
  const float* row = xn2 + (size_t)t * D_;
  float acc[8];
  #pragma unroll
  for (int e = 0; e < 8; ++e) acc[e] = 0.f;
  for (int i = 0; i < 16; ++i) {
    int d = l + i * 64;
    float xv = row[d];
    float4 w0 = *(const float4*)&rw[d * 8 + 0];
    float4 w1 = *(const float4*)&rw[d * 8 + 4];
    acc[0] = fmaf(xv, w0.x, acc[0]); acc[1] = fmaf(xv, w0.y, acc[1]);
    acc[2] = fmaf(xv, w0.z, acc[2]); acc[3] = fmaf(xv, w0.w, acc[3]);
    acc[4] = fmaf(xv, w1.x, acc[4]); acc[5] = fmaf(xv, w1.y, acc[5]);
    acc[6] = fmaf(xv, w1.z, acc[6]); acc[7] = fmaf(xv, w1.w, acc[7]);
  }
  #pragma unroll
  for (int off = 32; off > 0; off >>= 1)
    #pragma unroll
    for (int e = 0; e < 8; ++e) acc[e] += __shfl_xor(acc[e], off);
  if (l == 0) {
    float lg[8];
    #pragma unroll
    for (int e = 0; e < 8; ++e) lg[e] = acc[e] + rb[e];
    int i1 = 0;
    #pragma unroll
    for (int e = 1; e < 8; ++e) if (lg[e] > lg[i1]) i1 = e;
    int i2 = (i1 == 0) ? 1 : 0;
    #pragma unroll
    for (int e = 0; e < 8; ++e) if (e != i1 && lg[e] > lg[i2]) i2 = e;
    float wa = 1.f / (1.f + expf(lg[i2] - lg[i1]));
    float wb = 1.f - wa;
    int pa = atomicAdd(&cnt[i1], 1);
    int pb = atomicAdd(&cnt[i2], 1);
    list[i1 * T_ + pa] = t;
    list[i2 * T_ + pb] = t;
    eidx[2 * t] = i1; eidx[2 * t + 1] = i2;
    epos[2 * t] = pa; epos[2 * t + 1] = pb;
    ew[2 * t] = wa; ew[2 * t + 1] = wb;
  }
}

__global__ void k_offsets(const int* __restrict__ cnt, int* __restrict__ offs) {
  if (threadIdx.x == 0 && blockIdx.x == 0) {
    int tot = 0;
    for (int e = 0; e < E_; ++e) { offs[e] = tot; tot += cnt[e]; }
  }
}

// ---------------- bf16 MFMA GEMM for MoE ----------------
// MODE 0: h[slot] = gelu(xn2b[list] @ w1t[e]^T + b1[e]), K=1024, N=4096
// MODE 1: y[slot] = h[slot] @ w2t[e]^T + b2[e],           K=4096, N=1024
template <int MODE>
__global__ __launch_bounds__(256) void k_moe_gemm(const u16* __restrict__ Ab,
                                                  const u16* __restrict__ Wt,
                                                  const float* __restrict__ bias,
                                                  u16* __restrict__ outH,
                                                  float* __restrict__ outF,
                                                  const int* __restrict__ cnt,
                                                  const int* __restrict__ offs,
                                                  const int* __restrict__ list,
                                                  int N, int K) {
  int e = blockIdx.z;
  int myM = cnt[e];
  int m0 = blockIdx.x * 128;
  if (m0 >= myM) return;
  int n0 = blockIdx.y * 128;
  __shared__ __align__(16) u16 As[128 * 32];
  __shared__ __align__(16) u16 Bs[128 * 32];
  int tid = threadIdx.x, w = tid >> 6, l = tid & 63;
  int quad = l >> 4, l15 = l & 15;
  int koff = (l & 3) * 8;
  const u16* ap[2];
  const u16* bp[2];
  #pragma unroll
  for (int c = 0; c < 2; ++c) {
    int chunk = c * 4 + w;
    int r = m0 + chunk * 16 + (l >> 2);
    int rr = (r < myM) ? r : (myM - 1);
    if (MODE == 0) {
      int tok = list[e * T_ + rr];
      ap[c] = Ab + (size_t)tok * K + koff;
    } else {
      ap[c] = Ab + (size_t)(offs[e] + rr) * K + koff;
    }
    int nrow = n0 + chunk * 16 + (l >> 2);
    bp[c] = Wt + (size_t)e * N * K + (size_t)nrow * K + koff;
  }
  f32x4 acc[4][4] = {};
  int wm = (w & 1) * 64, wn = (w >> 1) * 64;
  for (int k0 = 0; k0 < K; k0 += 32) {
    __syncthreads();
    #pragma unroll
    for (int c = 0; c < 2; ++c) {
      gload16(ap[c] + k0, &As[(c * 4 + w) * 512]);
      gload16(bp[c] + k0, &Bs[(c * 4 + w) * 512]);
    }
    __syncthreads();
    bf16x8 af[4], bfv[4];
    #pragma unroll
    for (int i = 0; i < 4; ++i)
      af[i] = *(const bf16x8*)&As[(wm + i * 16 + l15) * 32 + quad * 8];
    #pragma unroll
    for (int j = 0; j < 4; ++j)
      bfv[j] = *(const bf16x8*)&Bs[(wn + j * 16 + l15) * 32 + quad * 8];
    #pragma unroll
    for (int i = 0; i < 4; ++i)
      #pragma unroll
      for (int j = 0; j < 4; ++j)
        acc[i][j] = __builtin_amdgcn_mfma_f32_16x16x32_bf16(af[i], bfv[j], acc[i][j], 0, 0, 0);
  }
  const float* bptr = bias + (size_t)e * N;
  #pragma unroll
  for (int i = 0; i < 4; ++i) {
    #pragma unroll
    for (int j = 0; j < 4; ++j) {
      int gn = n0 + wn + j * 16 + l15;
      float bv = bptr[gn];
      #pragma unroll
      for (int r = 0; r < 4; ++r) {
        int gm = m0 + wm + i * 16 + quad * 4 + r;
        if (gm < myM) {
          float vv = acc[i][j][r] + bv;
          if (MODE == 0)
            outH[(size_t)(offs[e] + gm) * N + gn] = f2b(gelu_t(vv));
          else
            outF[(size_t)(offs[e] + gm) * N + gn] = vv;
        }
      }
    }
  }
}

// ---------------- final combine ----------------
__global__ __launch_bounds__(256) void k_combine(const float* __restrict__ x1,
                                                 const float* __restrict__ y,
                                                 const int* __restrict__ eidx,
                                                 const int* __restrict__ epos,
                                                 const float* __restrict__ ew,
                                                 const int* __restrict__ offs,
                                                 float* __restrict__ out) {
  int t = blockIdx.x, tid = threadIdx.x;
  int e0 = eidx[2 * t], e1 = eidx[2 * t + 1];
  int s0 = offs[e0] + epos[2 * t];
  int s1 = offs[e1] + epos[2 * t + 1];
  float w0 = ew[2 * t], w1 = ew[2 * t + 1];
  int d = tid * 4;
  float4 a = *(const float4*)&x1[(size_t)t * D_ + d];
  float4 y0 = *(const float4*)&y[(size_t)s0 * D_ + d];
  float4 y1 = *(const float4*)&y[(size_t)s1 * D_ + d];
  float4 r;
  r.x = a.x + w0 * y0.x + w1 * y1.x;
  r.y = a.y + w0 * y0.y + w1 * y1.y;
  r.z = a.z + w0 * y0.z + w1 * y1.z;
  r.w = a.w + w0 * y0.w + w1 * y1.w;
  *(float4*)&out[(size_t)t * D_ + d] = r;
}

// ---------------- launch ----------------
extern "C" void kernel_launch(void* const* d_in, const int* in_sizes, int n_in,
                              void* d_out, int out_size, void* d_ws, size_t ws_size,
                              hipStream_t stream) {
  (void)in_sizes; (void)n_in; (void)out_size; (void)ws_size;
  const float* x    = (const float*)d_in[0];
  const float* sd   = (const float*)d_in[1];
  const float* ln1s = (const float*)d_in[2];
  const float* ln1b = (const float*)d_in[3];
  const float* wq   = (const float*)d_in[4];
  const float* bq   = (const float*)d_in[5];
  const float* wk   = (const float*)d_in[6];
  const float* bk   = (const float*)d_in[7];
  const float* wv   = (const float*)d_in[8];
  const float* bv   = (const float*)d_in[9];
  const float* wo   = (const float*)d_in[10];
  const float* bo   = (const float*)d_in[11];
  const float* td   = (const float*)d_in[12];
  const float* ln2s = (const float*)d_in[13];
  const float* ln2b = (const float*)d_in[14];
  const float* rw   = (const float*)d_in[15];
  const float* rb   = (const float*)d_in[16];
  const float* w1   = (const float*)d_in[17];
  const float* b1   = (const float*)d_in[18];
  const float* w2   = (const float*)d_in[19];
  const float* b2   = (const float*)d_in[20];
  float* out = (float*)d_out;

  const size_t MBy = 1024ull * 1024ull;
  char* ws = (char*)d_ws;
  float* xn   = (float*)(ws + 0);         // 16MB (also xn2 later)
  float* qb   = (float*)(ws + 16 * MBy);  // 16MB
  float* kb   = (float*)(ws + 32 * MBy);  // 4MB
  float* vb   = (float*)(ws + 36 * MBy);  // 4MB
  float* ob   = (float*)(ws + 40 * MBy);  // 16MB
  float* yb   = (float*)(ws + 16 * MBy);  // 32MB, aliases q/k/v/o after attention path done
  float* x1   = (float*)(ws + 56 * MBy);  // 16MB
  u16*   xn2b = (u16*)  (ws + 72 * MBy);  // 8MB
  u16*   w1t  = (u16*)  (ws + 80 * MBy);  // 64MB
  u16*   w2t  = (u16*)  (ws + 144 * MBy); // 64MB
  u16*   hb   = (u16*)  (ws + 208 * MBy); // 64MB
  int*   eidx = (int*)  (ws + 272 * MBy);
  int*   epos = eidx + 2 * T_;
  float* ew   = (float*)(epos + 2 * T_);
  int*   list = (int*)(ew + 2 * T_);
  int*   cnt  = list + E_ * T_;
  int*   offs = cnt + E_;
  float* xn2  = xn;

  k_zero<<<1, 64, 0, stream>>>(cnt);
  // w1 [E][D][F] -> w1t [E][F][D]; w2 [E][F][D] -> w2t [E][D][F]
  k_transpose<<<dim3(F_ / 32, D_ / 32, E_), dim3(32, 8), 0, stream>>>(w1, w1t, D_, F_);
  k_transpose<<<dim3(D_ / 32, F_ / 32, E_), dim3(32, 8), 0, stream>>>(w2, w2t, F_, D_);

  k_ln<<<T_, 256, 0, stream>>>(x, ln1s, ln1b, xn, nullptr);

  k_gemm_f32<<<dim3(T_ / 64, (H_ * HD_) / 64), 256, 0, stream>>>(xn, wq, bq, nullptr, qb, T_, H_ * HD_, D_);
  k_gemm_f32<<<dim3(T_ / 64, (G_ * HD_) / 64), 256, 0, stream>>>(xn, wk, bk, nullptr, kb, T_, G_ * HD_, D_);
  k_gemm_f32<<<dim3(T_ / 64, (G_ * HD_) / 64), 256, 0, stream>>>(xn, wv, bv, nullptr, vb, T_, G_ * HD_, D_);

  k_attn<<<dim3(S_ / 64, H_, B_), 256, 0, stream>>>(qb, kb, vb, sd, td, ob);

  k_gemm_f32<<<dim3(T_ / 64, D_ / 64), 256, 0, stream>>>(ob, wo, bo, x, x1, T_, D_, H_ * HD_);

  k_ln<<<T_, 256, 0, stream>>>(x1, ln2s, ln2b, xn2, xn2b);

  k_router<<<T_ / 4, 256, 0, stream>>>(xn2, rw, rb, eidx, epos, ew, cnt, list);
  k_offsets<<<1, 64, 0, stream>>>(cnt, offs);

  k_moe_gemm<0><<<dim3(32, F_ / 128, E_), 256, 0, stream>>>(xn2b, w1t, b1, hb, nullptr, cnt, offs, list, F_, D_);
  k_moe_gemm<1><<<dim3(32, D_ / 128, E_), 256, 0, stream>>>(hb, w2t, b2, nullptr, yb, cnt, offs, list, D_, F_);

  k_combine<<<T_, 256, 0, stream>>>(x1, yb, eidx, epos, ew, offs, out);
}

// Round 3
// 1672.836 us; speedup vs baseline: 1.4118x; 1.4118x over previous
//
#include <hip/hip_runtime.h>
#include <cstdint>
#include <cstddef>

typedef unsigned short u16;
typedef __bf16 bf16x8 __attribute__((ext_vector_type(8)));
typedef float f32x4 __attribute__((ext_vector_type(4)));

#define B_ 2
#define S_ 2048
#define D_ 1024
#define H_ 16
#define G_ 4
#define HD_ 64
#define E_ 8
#define F_ 4096
#define T_ 4096

__device__ __forceinline__ u16 f2b(float f) {
  unsigned u = __float_as_uint(f);
  return (u16)((u + 0x7fffu + ((u >> 16) & 1u)) >> 16);
}
__device__ __forceinline__ float b2f(u16 h) {
  return __uint_as_float(((unsigned)h) << 16);
}

__device__ __forceinline__ float gelu_t(float x) {
  float u = 0.7978845608028654f * (x + 0.044715f * x * x * x);
  float t = 1.f - 2.f / (__expf(2.f * u) + 1.f);
  return 0.5f * x * (1.f + t);
}

__device__ __forceinline__ void gload16(const void* g, void* l) {
  __builtin_amdgcn_global_load_lds((__attribute__((address_space(1))) void*)g,
                                   (__attribute__((address_space(3))) void*)l, 16, 0, 0);
}

// ---------------- small utility kernels ----------------

__global__ void k_zero(int* cnt) {
  if (threadIdx.x < E_) cnt[threadIdx.x] = 0;
}

// batched transpose + f32->bf16 (single): dst[z][C][R] = bf16(src[z][R][C])
__global__ __launch_bounds__(256) void k_transpose(const float* __restrict__ src,
                                                   u16* __restrict__ dst, int R, int C) {
  __shared__ u16 tile[32][33];
  int c0 = blockIdx.x * 32, r0 = blockIdx.y * 32;
  size_t zo = (size_t)blockIdx.z * (size_t)R * (size_t)C;
  int tx = threadIdx.x, ty = threadIdx.y;
  #pragma unroll
  for (int i = ty; i < 32; i += 8) {
    int r = r0 + i, cc = c0 + tx;
    float v = (r < R && cc < C) ? src[zo + (size_t)r * C + cc] : 0.f;
    tile[i][tx] = f2b(v);
  }
  __syncthreads();
  #pragma unroll
  for (int i = ty; i < 32; i += 8) {
    int cc = c0 + i, r = r0 + tx;
    if (cc < C && r < R) dst[zo + (size_t)cc * R + r] = tile[tx][i];
  }
}

// transpose + split f32 -> hi/lo bf16: dsth/dstl[C][R] = split(src[R][C])
__global__ __launch_bounds__(256) void k_split_transpose(const float* __restrict__ src,
                                                         u16* __restrict__ dsth,
                                                         u16* __restrict__ dstl,
                                                         int R, int C) {
  __shared__ float tile[32][33];
  int c0 = blockIdx.x * 32, r0 = blockIdx.y * 32;
  int tx = threadIdx.x, ty = threadIdx.y;
  #pragma unroll
  for (int i = ty; i < 32; i += 8) {
    int r = r0 + i, cc = c0 + tx;
    tile[i][tx] = (r < R && cc < C) ? src[(size_t)r * C + cc] : 0.f;
  }
  __syncthreads();
  #pragma unroll
  for (int i = ty; i < 32; i += 8) {
    int cc = c0 + i, r = r0 + tx;
    if (cc < C && r < R) {
      float v = tile[tx][i];
      u16 h = f2b(v);
      dsth[(size_t)cc * R + r] = h;
      dstl[(size_t)cc * R + r] = f2b(v - b2f(h));
    }
  }
}

// concat bq|bk|bv -> bqkv[1536]
__global__ void k_prep_bias(const float* bq, const float* bk, const float* bv, float* bqkv) {
  int i = blockIdx.x * 256 + threadIdx.x;
  if (i < 1024) bqkv[i] = bq[i];
  else if (i < 1280) bqkv[i] = bk[i - 1024];
  else if (i < 1536) bqkv[i] = bv[i - 1280];
}

// LayerNorm over D=1024; optional fp32 out, bf16 out, hi/lo split out
__global__ __launch_bounds__(256) void k_ln(const float* __restrict__ x,
                                            const float* __restrict__ sc,
                                            const float* __restrict__ bi,
                                            float* __restrict__ of,
                                            u16* __restrict__ ob,
                                            u16* __restrict__ oh,
                                            u16* __restrict__ ol) {
  int t = blockIdx.x, tid = threadIdx.x;
  const float* row = x + (size_t)t * D_;
  float4 v = *(const float4*)&row[tid * 4];
  float s = v.x + v.y + v.z + v.w;
  float ss = v.x * v.x + v.y * v.y + v.z * v.z + v.w * v.w;
  #pragma unroll
  for (int off = 32; off > 0; off >>= 1) {
    s += __shfl_xor(s, off);
    ss += __shfl_xor(ss, off);
  }
  __shared__ float red[8];
  if ((tid & 63) == 0) { red[(tid >> 6) * 2] = s; red[(tid >> 6) * 2 + 1] = ss; }
  __syncthreads();
  float S = red[0] + red[2] + red[4] + red[6];
  float SS = red[1] + red[3] + red[5] + red[7];
  float mu = S * (1.f / D_);
  float var = SS * (1.f / D_) - mu * mu;
  float rs = rsqrtf(var + 1e-6f);
  float4 scv = *(const float4*)&sc[tid * 4];
  float4 biv = *(const float4*)&bi[tid * 4];
  float o[4];
  o[0] = (v.x - mu) * rs * scv.x + biv.x;
  o[1] = (v.y - mu) * rs * scv.y + biv.y;
  o[2] = (v.z - mu) * rs * scv.z + biv.z;
  o[3] = (v.w - mu) * rs * scv.w + biv.w;
  size_t base = (size_t)t * D_ + tid * 4;
  if (of) *(float4*)&of[base] = make_float4(o[0], o[1], o[2], o[3]);
  if (ob) {
    ushort4 u;
    u.x = f2b(o[0]); u.y = f2b(o[1]); u.z = f2b(o[2]); u.w = f2b(o[3]);
    *(ushort4*)&ob[base] = u;
  }
  if (oh) {
    ushort4 uh, ulv;
    #pragma unroll
    for (int i = 0; i < 4; ++i) {
      u16 h = f2b(o[i]);
      u16 lo = f2b(o[i] - b2f(h));
      ((u16*)&uh)[i] = h;
      ((u16*)&ulv)[i] = lo;
    }
    *(ushort4*)&oh[base] = uh;
    *(ushort4*)&ol[base] = ulv;
  }
}

// ---------------- split-bf16 MFMA GEMM ----------------
// C[M,N] = (Ah+Al)[M,K] @ (Bh+Bl)[N,K]^T + bias  (3-term MFMA: hh + hl + lh)
// OUTMODE 0: write Ch/Cl (hi/lo bf16).  OUTMODE 1: write Cf = fp32 + res.
template <int OUTMODE>
__global__ __launch_bounds__(256) void k_gemm_split(const u16* __restrict__ Ah,
                                                    const u16* __restrict__ Al,
                                                    const u16* __restrict__ Bh,
                                                    const u16* __restrict__ Bl,
                                                    const float* __restrict__ bias,
                                                    const float* __restrict__ res,
                                                    u16* __restrict__ Ch,
                                                    u16* __restrict__ Cl,
                                                    float* __restrict__ Cf,
                                                    int M, int N, int K) {
  __shared__ __align__(16) u16 Ash[128 * 32], Asl[128 * 32];
  __shared__ __align__(16) u16 Bsh[128 * 32], Bsl[128 * 32];
  int tid = threadIdx.x, w = tid >> 6, l = tid & 63;
  int quad = l >> 4, l15 = l & 15;
  int m0 = blockIdx.x * 128, n0 = blockIdx.y * 128;
  int koff = (l & 3) * 8;
  const u16 *aph[2], *apl[2], *bph[2], *bpl[2];
  #pragma unroll
  for (int c = 0; c < 2; ++c) {
    int chunk = c * 4 + w;
    int row = m0 + chunk * 16 + (l >> 2);
    aph[c] = Ah + (size_t)row * K + koff;
    apl[c] = Al + (size_t)row * K + koff;
    int nrow = n0 + chunk * 16 + (l >> 2);
    bph[c] = Bh + (size_t)nrow * K + koff;
    bpl[c] = Bl + (size_t)nrow * K + koff;
  }
  f32x4 acc[4][4] = {};
  int wm = (w & 1) * 64, wn = (w >> 1) * 64;
  for (int k0 = 0; k0 < K; k0 += 32) {
    __syncthreads();
    #pragma unroll
    for (int c = 0; c < 2; ++c) {
      gload16(aph[c] + k0, &Ash[(c * 4 + w) * 512]);
      gload16(apl[c] + k0, &Asl[(c * 4 + w) * 512]);
      gload16(bph[c] + k0, &Bsh[(c * 4 + w) * 512]);
      gload16(bpl[c] + k0, &Bsl[(c * 4 + w) * 512]);
    }
    __syncthreads();
    bf16x8 ah[4], al_[4], bh[4], bl_[4];
    #pragma unroll
    for (int i = 0; i < 4; ++i) {
      ah[i] = *(const bf16x8*)&Ash[(wm + i * 16 + l15) * 32 + quad * 8];
      al_[i] = *(const bf16x8*)&Asl[(wm + i * 16 + l15) * 32 + quad * 8];
    }
    #pragma unroll
    for (int j = 0; j < 4; ++j) {
      bh[j] = *(const bf16x8*)&Bsh[(wn + j * 16 + l15) * 32 + quad * 8];
      bl_[j] = *(const bf16x8*)&Bsl[(wn + j * 16 + l15) * 32 + quad * 8];
    }
    #pragma unroll
    for (int i = 0; i < 4; ++i)
      #pragma unroll
      for (int j = 0; j < 4; ++j) {
        acc[i][j] = __builtin_amdgcn_mfma_f32_16x16x32_bf16(ah[i], bh[j], acc[i][j], 0, 0, 0);
        acc[i][j] = __builtin_amdgcn_mfma_f32_16x16x32_bf16(ah[i], bl_[j], acc[i][j], 0, 0, 0);
        acc[i][j] = __builtin_amdgcn_mfma_f32_16x16x32_bf16(al_[i], bh[j], acc[i][j], 0, 0, 0);
      }
  }
  #pragma unroll
  for (int i = 0; i < 4; ++i) {
    #pragma unroll
    for (int j = 0; j < 4; ++j) {
      int gn = n0 + wn + j * 16 + l15;
      float bv = bias[gn];
      #pragma unroll
      for (int r = 0; r < 4; ++r) {
        int gm = m0 + wm + i * 16 + quad * 4 + r;
        size_t idx = (size_t)gm * N + gn;
        float v = acc[i][j][r] + bv;
        if (OUTMODE == 0) {
          u16 h = f2b(v);
          Ch[idx] = h;
          Cl[idx] = f2b(v - b2f(h));
        } else {
          Cf[idx] = v + res[idx];
        }
      }
    }
  }
}

// ---------------- MFMA flash attention with session-delta decay ----------------
// grid (S/64, H, B), 256 threads = 4 waves; wave w handles queries [w*16, w*16+16).
// Q,K,V read from fused qkv buffer (hi/lo), row stride 1536.
#define AP 72  // padded u16 row stride for LDS tiles
__global__ __launch_bounds__(256) void k_attn_mfma(const u16* __restrict__ qkv_h,
                                                   const u16* __restrict__ qkv_l,
                                                   const float* __restrict__ sd,
                                                   const float* __restrict__ td,
                                                   u16* __restrict__ o_h,
                                                   u16* __restrict__ o_l) {
  __shared__ __align__(16) u16 Qh[64 * AP], Ql[64 * AP];
  __shared__ __align__(16) u16 Kh[64 * AP], Kl[64 * AP];
  __shared__ __align__(16) u16 Vth[64 * AP], Vtl[64 * AP];
  __shared__ __align__(16) u16 Ph[4][16 * AP], Pl[4][16 * AP];
  __shared__ float sds[64];
  int tid = threadIdx.x, w = tid >> 6, l = tid & 63;
  int quad = l >> 4, l15 = l & 15;
  int q0 = blockIdx.x * 64, h = blockIdx.y, b = blockIdx.z;
  int g = h >> 2;
  int r = tid >> 2, cb = (tid & 3) * 16;

  // stage Q tile [64 q][64 hd]
  {
    const u16* gq_h = qkv_h + (size_t)(b * S_ + q0 + r) * 1536 + h * HD_ + cb;
    const u16* gq_l = qkv_l + (size_t)(b * S_ + q0 + r) * 1536 + h * HD_ + cb;
    #pragma unroll
    for (int c = 0; c < 4; ++c) {
      *(ushort4*)&Qh[r * AP + cb + c * 4] = *(const ushort4*)&gq_h[c * 4];
      *(ushort4*)&Ql[r * AP + cb + c * 4] = *(const ushort4*)&gq_l[c * 4];
    }
  }
  __syncthreads();
  // hoist Q A-frags: row m = w*16 + l15, k = kk*32 + quad*8
  bf16x8 aqh[2], aql[2];
  #pragma unroll
  for (int kk = 0; kk < 2; ++kk) {
    aqh[kk] = *(const bf16x8*)&Qh[(w * 16 + l15) * AP + kk * 32 + quad * 8];
    aql[kk] = *(const bf16x8*)&Ql[(w * 16 + l15) * AP + kk * 32 + quad * 8];
  }
  float sp = log1pf(__expf(td[h]));
  float dq[4];
  #pragma unroll
  for (int i = 0; i < 4; ++i) dq[i] = sd[b * S_ + q0 + w * 16 + quad * 4 + i];

  float mr[4], lr[4];
  f32x4 oa[4] = {};
  #pragma unroll
  for (int i = 0; i < 4; ++i) { mr[i] = -3.0e38f; lr[i] = 0.f; }

  for (int s0 = 0; s0 < S_; s0 += 64) {
    // global loads for K,V rows (hi/lo) into regs
    const u16* gk_h = qkv_h + (size_t)(b * S_ + s0 + r) * 1536 + 1024 + g * HD_ + cb;
    const u16* gk_l = qkv_l + (size_t)(b * S_ + s0 + r) * 1536 + 1024 + g * HD_ + cb;
    const u16* gv_h = qkv_h + (size_t)(b * S_ + s0 + r) * 1536 + 1280 + g * HD_ + cb;
    const u16* gv_l = qkv_l + (size_t)(b * S_ + s0 + r) * 1536 + 1280 + g * HD_ + cb;
    ushort4 kh4[4], kl4[4];
    u16 vh[16], vl[16];
    #pragma unroll
    for (int c = 0; c < 4; ++c) {
      kh4[c] = *(const ushort4*)&gk_h[c * 4];
      kl4[c] = *(const ushort4*)&gk_l[c * 4];
      *(ushort4*)&vh[c * 4] = *(const ushort4*)&gv_h[c * 4];
      *(ushort4*)&vl[c * 4] = *(const ushort4*)&gv_l[c * 4];
    }
    __syncthreads();  // prior iteration's MFMA reads of K/Vt done
    #pragma unroll
    for (int c = 0; c < 4; ++c) {
      *(ushort4*)&Kh[r * AP + cb + c * 4] = kh4[c];
      *(ushort4*)&Kl[r * AP + cb + c * 4] = kl4[c];
    }
    #pragma unroll
    for (int i = 0; i < 16; ++i) {  // V transpose: Vt[hd][s]
      Vth[(cb + i) * AP + r] = vh[i];
      Vtl[(cb + i) * AP + r] = vl[i];
    }
    if (tid < 64) sds[tid] = sd[b * S_ + s0 + tid];
    __syncthreads();

    // QK^T: 4 key j-tiles, K=64 (2 ksteps), split 3-term
    f32x4 sc[4] = {};
    #pragma unroll
    for (int j = 0; j < 4; ++j) {
      #pragma unroll
      for (int kk = 0; kk < 2; ++kk) {
        bf16x8 bkh = *(const bf16x8*)&Kh[(j * 16 + l15) * AP + kk * 32 + quad * 8];
        bf16x8 bkl = *(const bf16x8*)&Kl[(j * 16 + l15) * AP + kk * 32 + quad * 8];
        sc[j] = __builtin_amdgcn_mfma_f32_16x16x32_bf16(aqh[kk], bkh, sc[j], 0, 0, 0);
        sc[j] = __builtin_amdgcn_mfma_f32_16x16x32_bf16(aqh[kk], bkl, sc[j], 0, 0, 0);
        sc[j] = __builtin_amdgcn_mfma_f32_16x16x32_bf16(aql[kk], bkh, sc[j], 0, 0, 0);
      }
    }
    // scale + decay; C-layout: col(key) = l15 + 16j, row(query) = quad*4 + reg
    float ds_[4];
    #pragma unroll
    for (int j = 0; j < 4; ++j) ds_[j] = sds[j * 16 + l15];
    float s_[4][4];
    #pragma unroll
    for (int j = 0; j < 4; ++j)
      #pragma unroll
      for (int i = 0; i < 4; ++i)
        s_[j][i] = sc[j][i] * 0.125f - sp * fabsf(dq[i] - ds_[j]);
    // online softmax per query row (reduce over l15 group)
    float mx[4];
    #pragma unroll
    for (int i = 0; i < 4; ++i)
      mx[i] = fmaxf(fmaxf(s_[0][i], s_[1][i]), fmaxf(s_[2][i], s_[3][i]));
    #pragma unroll
    for (int d = 1; d < 16; d <<= 1)
      #pragma unroll
      for (int i = 0; i < 4; ++i) mx[i] = fmaxf(mx[i], __shfl_xor(mx[i], d));
    float al[4], rsum[4], p[4][4];
    #pragma unroll
    for (int i = 0; i < 4; ++i) {
      float mn = fmaxf(mr[i], mx[i]);
      al[i] = __expf(mr[i] - mn);
      mr[i] = mn;
      rsum[i] = 0.f;
      #pragma unroll
      for (int j = 0; j < 4; ++j) { p[j][i] = __expf(s_[j][i] - mn); rsum[i] += p[j][i]; }
    }
    #pragma unroll
    for (int d = 1; d < 16; d <<= 1)
      #pragma unroll
      for (int i = 0; i < 4; ++i) rsum[i] += __shfl_xor(rsum[i], d);
    #pragma unroll
    for (int i = 0; i < 4; ++i) {
      lr[i] = lr[i] * al[i] + rsum[i];
      #pragma unroll
      for (int j = 0; j < 4; ++j) oa[j][i] *= al[i];
    }
    // P -> LDS (wave-private), hi/lo split
    #pragma unroll
    for (int j = 0; j < 4; ++j)
      #pragma unroll
      for (int i = 0; i < 4; ++i) {
        float pv = p[j][i];
        u16 hv = f2b(pv);
        Ph[w][(quad * 4 + i) * AP + j * 16 + l15] = hv;
        Pl[w][(quad * 4 + i) * AP + j * 16 + l15] = f2b(pv - b2f(hv));
      }
    // PV: A = P[q][s] (m=l15 query), B = Vt[hd][s]; split 3-term
    bf16x8 aph[2], apl[2];
    #pragma unroll
    for (int kk = 0; kk < 2; ++kk) {
      aph[kk] = *(const bf16x8*)&Ph[w][l15 * AP + kk * 32 + quad * 8];
      apl[kk] = *(const bf16x8*)&Pl[w][l15 * AP + kk * 32 + quad * 8];
    }
    #pragma unroll
    for (int j = 0; j < 4; ++j) {
      #pragma unroll
      for (int kk = 0; kk < 2; ++kk) {
        bf16x8 bvh = *(const bf16x8*)&Vth[(j * 16 + l15) * AP + kk * 32 + quad * 8];
        bf16x8 bvl = *(const bf16x8*)&Vtl[(j * 16 + l15) * AP + kk * 32 + quad * 8];
        oa[j] = __builtin_amdgcn_mfma_f32_16x16x32_bf16(aph[kk], bvh, oa[j], 0, 0, 0);
        oa[j] = __builtin_amdgcn_mfma_f32_16x16x32_bf16(aph[kk], bvl, oa[j], 0, 0, 0);
        oa[j] = __builtin_amdgcn_mfma_f32_16x16x32_bf16(apl[kk], bvh, oa[j], 0, 0, 0);
      }
    }
  }
  // epilogue: O / l, write hi/lo
  #pragma unroll
  for (int i = 0; i < 4; ++i) {
    float inv = 1.f / lr[i];
    int q = b * S_ + q0 + w * 16 + quad * 4 + i;
    #pragma unroll
    for (int j = 0; j < 4; ++j) {
      float ov = oa[j][i] * inv;
      size_t idx = (size_t)q * (H_ * HD_) + h * HD_ + j * 16 + l15;
      u16 hv = f2b(ov);
      o_h[idx] = hv;
      o_l[idx] = f2b(ov - b2f(hv));
    }
  }
}

// ---------------- router ----------------
__global__ __launch_bounds__(256) void k_router(const float* __restrict__ xn2,
                                                const float* __restrict__ rw,
                                                const float* __restrict__ rb,
                                                int* __restrict__ eidx, int* __restrict__ epos,
                                                float* __restrict__ ew, int* __restrict__ cnt,
                                                int* __restrict__ list) {
  int t = blockIdx.x * 4 + (threadIdx.x >> 6);
  int l = threadIdx.x & 63;
  const float* row = xn2 + (size_t)t * D_;
  float acc[8];
  #pragma unroll
  for (int e = 0; e < 8; ++e) acc[e] = 0.f;
  for (int i = 0; i < 16; ++i) {
    int d = l + i * 64;
    float xv = row[d];
    float4 w0 = *(const float4*)&rw[d * 8 + 0];
    float4 w1 = *(const float4*)&rw[d * 8 + 4];
    acc[0] = fmaf(xv, w0.x, acc[0]); acc[1] = fmaf(xv, w0.y, acc[1]);
    acc[2] = fmaf(xv, w0.z, acc[2]); acc[3] = fmaf(xv, w0.w, acc[3]);
    acc[4] = fmaf(xv, w1.x, acc[4]); acc[5] = fmaf(xv, w1.y, acc[5]);
    acc[6] = fmaf(xv, w1.z, acc[6]); acc[7] = fmaf(xv, w1.w, acc[7]);
  }
  #pragma unroll
  for (int off = 32; off > 0; off >>= 1)
    #pragma unroll
    for (int e = 0; e < 8; ++e) acc[e] += __shfl_xor(acc[e], off);
  if (l == 0) {
    float lg[8];
    #pragma unroll
    for (int e = 0; e < 8; ++e) lg[e] = acc[e] + rb[e];
    int i1 = 0;
    #pragma unroll
    for (int e = 1; e < 8; ++e) if (lg[e] > lg[i1]) i1 = e;
    int i2 = (i1 == 0) ? 1 : 0;
    #pragma unroll
    for (int e = 0; e < 8; ++e) if (e != i1 && lg[e] > lg[i2]) i2 = e;
    float wa = 1.f / (1.f + __expf(lg[i2] - lg[i1]));
    float wb = 1.f - wa;
    int pa = atomicAdd(&cnt[i1], 1);
    int pb = atomicAdd(&cnt[i2], 1);
    list[i1 * T_ + pa] = t;
    list[i2 * T_ + pb] = t;
    eidx[2 * t] = i1; eidx[2 * t + 1] = i2;
    epos[2 * t] = pa; epos[2 * t + 1] = pb;
    ew[2 * t] = wa; ew[2 * t + 1] = wb;
  }
}

__global__ void k_offsets(const int* __restrict__ cnt, int* __restrict__ offs) {
  if (threadIdx.x == 0 && blockIdx.x == 0) {
    int tot = 0;
    for (int e = 0; e < E_; ++e) { offs[e] = tot; tot += cnt[e]; }
  }
}

// ---------------- bf16 MFMA GEMM for MoE ----------------
// MODE 0: h[slot] = gelu(xn2b[list] @ w1t[e]^T + b1[e]) -> u16
// MODE 1: y[slot] = h[slot] @ w2t[e]^T + b2[e]          -> u16
template <int MODE>
__global__ __launch_bounds__(256) void k_moe_gemm(const u16* __restrict__ Ab,
                                                  const u16* __restrict__ Wt,
                                                  const float* __restrict__ bias,
                                                  u16* __restrict__ outU,
                                                  const int* __restrict__ cnt,
                                                  const int* __restrict__ offs,
                                                  const int* __restrict__ list,
                                                  int N, int K) {
  int e = blockIdx.z;
  int myM = cnt[e];
  int m0 = blockIdx.x * 128;
  if (m0 >= myM) return;
  int n0 = blockIdx.y * 128;
  __shared__ __align__(16) u16 As[128 * 32];
  __shared__ __align__(16) u16 Bs[128 * 32];
  int tid = threadIdx.x, w = tid >> 6, l = tid & 63;
  int quad = l >> 4, l15 = l & 15;
  int koff = (l & 3) * 8;
  const u16* ap[2];
  const u16* bp[2];
  #pragma unroll
  for (int c = 0; c < 2; ++c) {
    int chunk = c * 4 + w;
    int r = m0 + chunk * 16 + (l >> 2);
    int rr = (r < myM) ? r : (myM - 1);
    if (MODE == 0) {
      int tok = list[e * T_ + rr];
      ap[c] = Ab + (size_t)tok * K + koff;
    } else {
      ap[c] = Ab + (size_t)(offs[e] + rr) * K + koff;
    }
    int nrow = n0 + chunk * 16 + (l >> 2);
    bp[c] = Wt + (size_t)e * N * K + (size_t)nrow * K + koff;
  }
  f32x4 acc[4][4] = {};
  int wm = (w & 1) * 64, wn = (w >> 1) * 64;
  for (int k0 = 0; k0 < K; k0 += 32) {
    __syncthreads();
    #pragma unroll
    for (int c = 0; c < 2; ++c) {
      gload16(ap[c] + k0, &As[(c * 4 + w) * 512]);
      gload16(bp[c] + k0, &Bs[(c * 4 + w) * 512]);
    }
    __syncthreads();
    bf16x8 af[4], bfv[4];
    #pragma unroll
    for (int i = 0; i < 4; ++i)
      af[i] = *(const bf16x8*)&As[(wm + i * 16 + l15) * 32 + quad * 8];
    #pragma unroll
    for (int j = 0; j < 4; ++j)
      bfv[j] = *(const bf16x8*)&Bs[(wn + j * 16 + l15) * 32 + quad * 8];
    #pragma unroll
    for (int i = 0; i < 4; ++i)
      #pragma unroll
      for (int j = 0; j < 4; ++j)
        acc[i][j] = __builtin_amdgcn_mfma_f32_16x16x32_bf16(af[i], bfv[j], acc[i][j], 0, 0, 0);
  }
  const float* bptr = bias + (size_t)e * N;
  #pragma unroll
  for (int i = 0; i < 4; ++i) {
    #pragma unroll
    for (int j = 0; j < 4; ++j) {
      int gn = n0 + wn + j * 16 + l15;
      float bv = bptr[gn];
      #pragma unroll
      for (int r = 0; r < 4; ++r) {
        int gm = m0 + wm + i * 16 + quad * 4 + r;
        if (gm < myM) {
          float vv = acc[i][j][r] + bv;
          if (MODE == 0) vv = gelu_t(vv);
          outU[(size_t)(offs[e] + gm) * N + gn] = f2b(vv);
        }
      }
    }
  }
}

// ---------------- final combine ----------------
__global__ __launch_bounds__(256) void k_combine(const float* __restrict__ x1,
                                                 const u16* __restrict__ y,
                                                 const int* __restrict__ eidx,
                                                 const int* __restrict__ epos,
                                                 const float* __restrict__ ew,
                                                 const int* __restrict__ offs,
                                                 float* __restrict__ out) {
  int t = blockIdx.x, tid = threadIdx.x;
  int e0 = eidx[2 * t], e1 = eidx[2 * t + 1];
  int s0 = offs[e0] + epos[2 * t];
  int s1 = offs[e1] + epos[2 * t + 1];
  float w0 = ew[2 * t], w1 = ew[2 * t + 1];
  int d = tid * 4;
  float4 a = *(const float4*)&x1[(size_t)t * D_ + d];
  ushort4 y0 = *(const ushort4*)&y[(size_t)s0 * D_ + d];
  ushort4 y1 = *(const ushort4*)&y[(size_t)s1 * D_ + d];
  float4 r;
  r.x = a.x + w0 * b2f(y0.x) + w1 * b2f(y1.x);
  r.y = a.y + w0 * b2f(y0.y) + w1 * b2f(y1.y);
  r.z = a.z + w0 * b2f(y0.z) + w1 * b2f(y1.z);
  r.w = a.w + w0 * b2f(y0.w) + w1 * b2f(y1.w);
  *(float4*)&out[(size_t)t * D_ + d] = r;
}

// ---------------- launch ----------------
extern "C" void kernel_launch(void* const* d_in, const int* in_sizes, int n_in,
                              void* d_out, int out_size, void* d_ws, size_t ws_size,
                              hipStream_t stream) {
  (void)in_sizes; (void)n_in; (void)out_size; (void)ws_size;
  const float* x    = (const float*)d_in[0];
  const float* sd   = (const float*)d_in[1];
  const float* ln1s = (const float*)d_in[2];
  const float* ln1b = (const float*)d_in[3];
  const float* wq   = (const float*)d_in[4];
  const float* bq   = (const float*)d_in[5];
  const float* wk   = (const float*)d_in[6];
  const float* bk   = (const float*)d_in[7];
  const float* wv   = (const float*)d_in[8];
  const float* bv   = (const float*)d_in[9];
  const float* wo   = (const float*)d_in[10];
  const float* bo   = (const float*)d_in[11];
  const float* td   = (const float*)d_in[12];
  const float* ln2s = (const float*)d_in[13];
  const float* ln2b = (const float*)d_in[14];
  const float* rw   = (const float*)d_in[15];
  const float* rb   = (const float*)d_in[16];
  const float* w1   = (const float*)d_in[17];
  const float* b1   = (const float*)d_in[18];
  const float* w2   = (const float*)d_in[19];
  const float* b2   = (const float*)d_in[20];
  float* out = (float*)d_out;

  const size_t MBy = 1024ull * 1024ull;
  char* ws = (char*)d_ws;
  u16*   w1t   = (u16*)(ws + 0);          // 64MB   [prep -> moe1]
  u16*   w2t   = (u16*)(ws + 64 * MBy);   // 64MB   [prep -> moe2]
  u16*   hb    = (u16*)(ws + 128 * MBy);  // 64MB   [moe1 -> moe2]
  float* xn2   = (float*)(ws + 128 * MBy);// 16MB   aliases hb (dead before moe1)
  u16*   wqkvTh= (u16*)(ws + 192 * MBy);  // 3MB
  u16*   wqkvTl= (u16*)(ws + 195 * MBy);  // 3MB
  u16*   woTh  = (u16*)(ws + 198 * MBy);  // 2MB
  u16*   woTl  = (u16*)(ws + 200 * MBy);  // 2MB
  float* bqkv  = (float*)(ws + 202 * MBy);// 6KB
  int*   eidx  = (int*)(ws + 202 * MBy + 65536);
  int*   epos  = eidx + 2 * T_;
  float* ew    = (float*)(epos + 2 * T_);
  int*   list  = (int*)(ew + 2 * T_);
  int*   cnt   = list + E_ * T_;
  int*   offs  = cnt + E_;
  u16*   xn_h  = (u16*)(ws + 203 * MBy);  // 8MB    [ln1 -> qkv gemm]
  u16*   xn_l  = (u16*)(ws + 211 * MBy);  // 8MB
  u16*   xn2b  = (u16*)(ws + 203 * MBy);  // 8MB    aliases xn_h (dead)
  u16*   qkv_h = (u16*)(ws + 219 * MBy);  // 13MB   [qkv -> attn]
  u16*   qkv_l = (u16*)(ws + 232 * MBy);  // 13MB
  u16*   yb    = (u16*)(ws + 219 * MBy);  // 16MB   aliases qkv (dead after attn)
  u16*   o_h   = (u16*)(ws + 245 * MBy);  // 8MB    [attn -> outproj]
  u16*   o_l   = (u16*)(ws + 253 * MBy);  // 8MB
  float* x1    = (float*)(ws + 261 * MBy);// 16MB   [outproj -> combine]

  k_zero<<<1, 64, 0, stream>>>(cnt);
  // MoE weights: w1 [E][D][F] -> w1t [E][F][D]; w2 [E][F][D] -> w2t [E][D][F]
  k_transpose<<<dim3(F_ / 32, D_ / 32, E_), dim3(32, 8), 0, stream>>>(w1, w1t, D_, F_);
  k_transpose<<<dim3(D_ / 32, F_ / 32, E_), dim3(32, 8), 0, stream>>>(w2, w2t, F_, D_);
  // attention weights: split-transpose to [N][K]
  k_split_transpose<<<dim3(1024 / 32, 1024 / 32), dim3(32, 8), 0, stream>>>(wq, wqkvTh, wqkvTl, 1024, 1024);
  k_split_transpose<<<dim3(256 / 32, 1024 / 32), dim3(32, 8), 0, stream>>>(wk, wqkvTh + 1024 * 1024, wqkvTl + 1024 * 1024, 1024, 256);
  k_split_transpose<<<dim3(256 / 32, 1024 / 32), dim3(32, 8), 0, stream>>>(wv, wqkvTh + 1280 * 1024, wqkvTl + 1280 * 1024, 1024, 256);
  k_split_transpose<<<dim3(1024 / 32, 1024 / 32), dim3(32, 8), 0, stream>>>(wo, woTh, woTl, 1024, 1024);
  k_prep_bias<<<6, 256, 0, stream>>>(bq, bk, bv, bqkv);

  k_ln<<<T_, 256, 0, stream>>>(x, ln1s, ln1b, nullptr, nullptr, xn_h, xn_l);

  // fused QKV projection: [T,1536] = xn @ [wq|wk|wv]
  k_gemm_split<0><<<dim3(T_ / 128, 1536 / 128), 256, 0, stream>>>(
      xn_h, xn_l, wqkvTh, wqkvTl, bqkv, nullptr, qkv_h, qkv_l, nullptr, T_, 1536, 1024);

  k_attn_mfma<<<dim3(S_ / 64, H_, B_), 256, 0, stream>>>(qkv_h, qkv_l, sd, td, o_h, o_l);

  // out-proj + residual: x1 = o @ wo + bo + x
  k_gemm_split<1><<<dim3(T_ / 128, 1024 / 128), 256, 0, stream>>>(
      o_h, o_l, woTh, woTl, bo, x, nullptr, nullptr, x1, T_, 1024, 1024);

  k_ln<<<T_, 256, 0, stream>>>(x1, ln2s, ln2b, xn2, xn2b, nullptr, nullptr);

  k_router<<<T_ / 4, 256, 0, stream>>>(xn2, rw, rb, eidx, epos, ew, cnt, list);
  k_offsets<<<1, 64, 0, stream>>>(cnt, offs);

  k_moe_gemm<0><<<dim3(32, F_ / 128, E_), 256, 0, stream>>>(xn2b, w1t, b1, hb, cnt, offs, list, F_, D_);
  k_moe_gemm<1><<<dim3(32, D_ / 128, E_), 256, 0, stream>>>(hb, w2t, b2, yb, cnt, offs, list, D_, F_);

  k_combine<<<T_, 256, 0, stream>>>(x1, yb, eidx, epos, ew, offs, out);
}

// Round 4
// 1630.336 us; speedup vs baseline: 1.4486x; 1.0261x over previous
//
#include <hip/hip_runtime.h>
#include <cstdint>
#include <cstddef>

typedef unsigned short u16;
typedef __bf16 bf16x8 __attribute__((ext_vector_type(8)));
typedef float f32x4 __attribute__((ext_vector_type(4)));

#define B_ 2
#define S_ 2048
#define D_ 1024
#define H_ 16
#define G_ 4
#define HD_ 64
#define E_ 8
#define F_ 4096
#define T_ 4096

__device__ __forceinline__ u16 f2b(float f) {
  unsigned u = __float_as_uint(f);
  return (u16)((u + 0x7fffu + ((u >> 16) & 1u)) >> 16);
}
__device__ __forceinline__ float b2f(u16 h) {
  return __uint_as_float(((unsigned)h) << 16);
}

__device__ __forceinline__ float gelu_t(float x) {
  float u = 0.7978845608028654f * (x + 0.044715f * x * x * x);
  float t = 1.f - 2.f / (__expf(2.f * u) + 1.f);
  return 0.5f * x * (1.f + t);
}

__device__ __forceinline__ void gload16(const void* g, void* l) {
  __builtin_amdgcn_global_load_lds((__attribute__((address_space(1))) void*)g,
                                   (__attribute__((address_space(3))) void*)l, 16, 0, 0);
}

// ---------------- small utility kernels ----------------

__global__ void k_zero(int* cnt) {
  if (threadIdx.x < E_) cnt[threadIdx.x] = 0;
}

// batched transpose + f32->bf16 (single): dst[z][C][R] = bf16(src[z][R][C])
__global__ __launch_bounds__(256) void k_transpose(const float* __restrict__ src,
                                                   u16* __restrict__ dst, int R, int C) {
  __shared__ u16 tile[32][33];
  int c0 = blockIdx.x * 32, r0 = blockIdx.y * 32;
  size_t zo = (size_t)blockIdx.z * (size_t)R * (size_t)C;
  int tx = threadIdx.x, ty = threadIdx.y;
  #pragma unroll
  for (int i = ty; i < 32; i += 8) {
    int r = r0 + i, cc = c0 + tx;
    float v = (r < R && cc < C) ? src[zo + (size_t)r * C + cc] : 0.f;
    tile[i][tx] = f2b(v);
  }
  __syncthreads();
  #pragma unroll
  for (int i = ty; i < 32; i += 8) {
    int cc = c0 + i, r = r0 + tx;
    if (cc < C && r < R) dst[zo + (size_t)cc * R + r] = tile[tx][i];
  }
}

// transpose + split f32 -> hi/lo bf16: dsth/dstl[C][R] = split(src[R][C])
__global__ __launch_bounds__(256) void k_split_transpose(const float* __restrict__ src,
                                                         u16* __restrict__ dsth,
                                                         u16* __restrict__ dstl,
                                                         int R, int C) {
  __shared__ float tile[32][33];
  int c0 = blockIdx.x * 32, r0 = blockIdx.y * 32;
  int tx = threadIdx.x, ty = threadIdx.y;
  #pragma unroll
  for (int i = ty; i < 32; i += 8) {
    int r = r0 + i, cc = c0 + tx;
    tile[i][tx] = (r < R && cc < C) ? src[(size_t)r * C + cc] : 0.f;
  }
  __syncthreads();
  #pragma unroll
  for (int i = ty; i < 32; i += 8) {
    int cc = c0 + i, r = r0 + tx;
    if (cc < C && r < R) {
      float v = tile[tx][i];
      u16 h = f2b(v);
      dsth[(size_t)cc * R + r] = h;
      dstl[(size_t)cc * R + r] = f2b(v - b2f(h));
    }
  }
}

// concat bq|bk|bv -> bqkv[1536]
__global__ void k_prep_bias(const float* bq, const float* bk, const float* bv, float* bqkv) {
  int i = blockIdx.x * 256 + threadIdx.x;
  if (i < 1024) bqkv[i] = bq[i];
  else if (i < 1280) bqkv[i] = bk[i - 1024];
  else if (i < 1536) bqkv[i] = bv[i - 1280];
}

// LayerNorm over D=1024; optional fp32 out, bf16 out, hi/lo split out
__global__ __launch_bounds__(256) void k_ln(const float* __restrict__ x,
                                            const float* __restrict__ sc,
                                            const float* __restrict__ bi,
                                            float* __restrict__ of,
                                            u16* __restrict__ ob,
                                            u16* __restrict__ oh,
                                            u16* __restrict__ ol) {
  int t = blockIdx.x, tid = threadIdx.x;
  const float* row = x + (size_t)t * D_;
  float4 v = *(const float4*)&row[tid * 4];
  float s = v.x + v.y + v.z + v.w;
  float ss = v.x * v.x + v.y * v.y + v.z * v.z + v.w * v.w;
  #pragma unroll
  for (int off = 32; off > 0; off >>= 1) {
    s += __shfl_xor(s, off);
    ss += __shfl_xor(ss, off);
  }
  __shared__ float red[8];
  if ((tid & 63) == 0) { red[(tid >> 6) * 2] = s; red[(tid >> 6) * 2 + 1] = ss; }
  __syncthreads();
  float S = red[0] + red[2] + red[4] + red[6];
  float SS = red[1] + red[3] + red[5] + red[7];
  float mu = S * (1.f / D_);
  float var = SS * (1.f / D_) - mu * mu;
  float rs = rsqrtf(var + 1e-6f);
  float4 scv = *(const float4*)&sc[tid * 4];
  float4 biv = *(const float4*)&bi[tid * 4];
  float o[4];
  o[0] = (v.x - mu) * rs * scv.x + biv.x;
  o[1] = (v.y - mu) * rs * scv.y + biv.y;
  o[2] = (v.z - mu) * rs * scv.z + biv.z;
  o[3] = (v.w - mu) * rs * scv.w + biv.w;
  size_t base = (size_t)t * D_ + tid * 4;
  if (of) *(float4*)&of[base] = make_float4(o[0], o[1], o[2], o[3]);
  if (ob) {
    ushort4 u;
    u.x = f2b(o[0]); u.y = f2b(o[1]); u.z = f2b(o[2]); u.w = f2b(o[3]);
    *(ushort4*)&ob[base] = u;
  }
  if (oh) {
    ushort4 uh, ulv;
    #pragma unroll
    for (int i = 0; i < 4; ++i) {
      u16 h = f2b(o[i]);
      u16 lo = f2b(o[i] - b2f(h));
      ((u16*)&uh)[i] = h;
      ((u16*)&ulv)[i] = lo;
    }
    *(ushort4*)&oh[base] = uh;
    *(ushort4*)&ol[base] = ulv;
  }
}

// ---------------- split-bf16 MFMA GEMM ----------------
// C[M,N] = (Ah+Al)[M,K] @ (Bh+Bl)[N,K]^T + bias  (3-term MFMA: hh + hl + lh)
// OUTMODE 0: write Ch/Cl (hi/lo bf16).  OUTMODE 1: write Cf = fp32 + res.
template <int OUTMODE>
__global__ __launch_bounds__(256) void k_gemm_split(const u16* __restrict__ Ah,
                                                    const u16* __restrict__ Al,
                                                    const u16* __restrict__ Bh,
                                                    const u16* __restrict__ Bl,
                                                    const float* __restrict__ bias,
                                                    const float* __restrict__ res,
                                                    u16* __restrict__ Ch,
                                                    u16* __restrict__ Cl,
                                                    float* __restrict__ Cf,
                                                    int M, int N, int K) {
  __shared__ __align__(16) u16 Ash[128 * 32], Asl[128 * 32];
  __shared__ __align__(16) u16 Bsh[128 * 32], Bsl[128 * 32];
  int tid = threadIdx.x, w = tid >> 6, l = tid & 63;
  int quad = l >> 4, l15 = l & 15;
  int m0 = blockIdx.x * 128, n0 = blockIdx.y * 128;
  int koff = (l & 3) * 8;
  const u16 *aph[2], *apl[2], *bph[2], *bpl[2];
  #pragma unroll
  for (int c = 0; c < 2; ++c) {
    int chunk = c * 4 + w;
    int row = m0 + chunk * 16 + (l >> 2);
    aph[c] = Ah + (size_t)row * K + koff;
    apl[c] = Al + (size_t)row * K + koff;
    int nrow = n0 + chunk * 16 + (l >> 2);
    bph[c] = Bh + (size_t)nrow * K + koff;
    bpl[c] = Bl + (size_t)nrow * K + koff;
  }
  f32x4 acc[4][4] = {};
  int wm = (w & 1) * 64, wn = (w >> 1) * 64;
  for (int k0 = 0; k0 < K; k0 += 32) {
    __syncthreads();
    #pragma unroll
    for (int c = 0; c < 2; ++c) {
      gload16(aph[c] + k0, &Ash[(c * 4 + w) * 512]);
      gload16(apl[c] + k0, &Asl[(c * 4 + w) * 512]);
      gload16(bph[c] + k0, &Bsh[(c * 4 + w) * 512]);
      gload16(bpl[c] + k0, &Bsl[(c * 4 + w) * 512]);
    }
    __syncthreads();
    bf16x8 ah[4], al_[4], bh[4], bl_[4];
    #pragma unroll
    for (int i = 0; i < 4; ++i) {
      ah[i] = *(const bf16x8*)&Ash[(wm + i * 16 + l15) * 32 + quad * 8];
      al_[i] = *(const bf16x8*)&Asl[(wm + i * 16 + l15) * 32 + quad * 8];
    }
    #pragma unroll
    for (int j = 0; j < 4; ++j) {
      bh[j] = *(const bf16x8*)&Bsh[(wn + j * 16 + l15) * 32 + quad * 8];
      bl_[j] = *(const bf16x8*)&Bsl[(wn + j * 16 + l15) * 32 + quad * 8];
    }
    #pragma unroll
    for (int i = 0; i < 4; ++i)
      #pragma unroll
      for (int j = 0; j < 4; ++j) {
        acc[i][j] = __builtin_amdgcn_mfma_f32_16x16x32_bf16(ah[i], bh[j], acc[i][j], 0, 0, 0);
        acc[i][j] = __builtin_amdgcn_mfma_f32_16x16x32_bf16(ah[i], bl_[j], acc[i][j], 0, 0, 0);
        acc[i][j] = __builtin_amdgcn_mfma_f32_16x16x32_bf16(al_[i], bh[j], acc[i][j], 0, 0, 0);
      }
  }
  #pragma unroll
  for (int i = 0; i < 4; ++i) {
    #pragma unroll
    for (int j = 0; j < 4; ++j) {
      int gn = n0 + wn + j * 16 + l15;
      float bv = bias[gn];
      #pragma unroll
      for (int r = 0; r < 4; ++r) {
        int gm = m0 + wm + i * 16 + quad * 4 + r;
        size_t idx = (size_t)gm * N + gn;
        float v = acc[i][j][r] + bv;
        if (OUTMODE == 0) {
          u16 h = f2b(v);
          Ch[idx] = h;
          Cl[idx] = f2b(v - b2f(h));
        } else {
          Cf[idx] = v + res[idx];
        }
      }
    }
  }
}

// ---------------- MFMA flash attention with session-delta decay ----------------
#define AP 72  // padded u16 row stride for LDS tiles
__global__ __launch_bounds__(256) void k_attn_mfma(const u16* __restrict__ qkv_h,
                                                   const u16* __restrict__ qkv_l,
                                                   const float* __restrict__ sd,
                                                   const float* __restrict__ td,
                                                   u16* __restrict__ o_h,
                                                   u16* __restrict__ o_l) {
  __shared__ __align__(16) u16 Qh[64 * AP], Ql[64 * AP];
  __shared__ __align__(16) u16 Kh[64 * AP], Kl[64 * AP];
  __shared__ __align__(16) u16 Vth[64 * AP], Vtl[64 * AP];
  __shared__ __align__(16) u16 Ph[4][16 * AP], Pl[4][16 * AP];
  __shared__ float sds[64];
  int tid = threadIdx.x, w = tid >> 6, l = tid & 63;
  int quad = l >> 4, l15 = l & 15;
  int q0 = blockIdx.x * 64, h = blockIdx.y, b = blockIdx.z;
  int g = h >> 2;
  int r = tid >> 2, cb = (tid & 3) * 16;

  {
    const u16* gq_h = qkv_h + (size_t)(b * S_ + q0 + r) * 1536 + h * HD_ + cb;
    const u16* gq_l = qkv_l + (size_t)(b * S_ + q0 + r) * 1536 + h * HD_ + cb;
    #pragma unroll
    for (int c = 0; c < 4; ++c) {
      *(ushort4*)&Qh[r * AP + cb + c * 4] = *(const ushort4*)&gq_h[c * 4];
      *(ushort4*)&Ql[r * AP + cb + c * 4] = *(const ushort4*)&gq_l[c * 4];
    }
  }
  __syncthreads();
  bf16x8 aqh[2], aql[2];
  #pragma unroll
  for (int kk = 0; kk < 2; ++kk) {
    aqh[kk] = *(const bf16x8*)&Qh[(w * 16 + l15) * AP + kk * 32 + quad * 8];
    aql[kk] = *(const bf16x8*)&Ql[(w * 16 + l15) * AP + kk * 32 + quad * 8];
  }
  float sp = log1pf(__expf(td[h]));
  float dq[4];
  #pragma unroll
  for (int i = 0; i < 4; ++i) dq[i] = sd[b * S_ + q0 + w * 16 + quad * 4 + i];

  float mr[4], lr[4];
  f32x4 oa[4] = {};
  #pragma unroll
  for (int i = 0; i < 4; ++i) { mr[i] = -3.0e38f; lr[i] = 0.f; }

  for (int s0 = 0; s0 < S_; s0 += 64) {
    const u16* gk_h = qkv_h + (size_t)(b * S_ + s0 + r) * 1536 + 1024 + g * HD_ + cb;
    const u16* gk_l = qkv_l + (size_t)(b * S_ + s0 + r) * 1536 + 1024 + g * HD_ + cb;
    const u16* gv_h = qkv_h + (size_t)(b * S_ + s0 + r) * 1536 + 1280 + g * HD_ + cb;
    const u16* gv_l = qkv_l + (size_t)(b * S_ + s0 + r) * 1536 + 1280 + g * HD_ + cb;
    ushort4 kh4[4], kl4[4];
    u16 vh[16], vl[16];
    #pragma unroll
    for (int c = 0; c < 4; ++c) {
      kh4[c] = *(const ushort4*)&gk_h[c * 4];
      kl4[c] = *(const ushort4*)&gk_l[c * 4];
      *(ushort4*)&vh[c * 4] = *(const ushort4*)&gv_h[c * 4];
      *(ushort4*)&vl[c * 4] = *(const ushort4*)&gv_l[c * 4];
    }
    __syncthreads();
    #pragma unroll
    for (int c = 0; c < 4; ++c) {
      *(ushort4*)&Kh[r * AP + cb + c * 4] = kh4[c];
      *(ushort4*)&Kl[r * AP + cb + c * 4] = kl4[c];
    }
    #pragma unroll
    for (int i = 0; i < 16; ++i) {
      Vth[(cb + i) * AP + r] = vh[i];
      Vtl[(cb + i) * AP + r] = vl[i];
    }
    if (tid < 64) sds[tid] = sd[b * S_ + s0 + tid];
    __syncthreads();

    f32x4 sc[4] = {};
    #pragma unroll
    for (int j = 0; j < 4; ++j) {
      #pragma unroll
      for (int kk = 0; kk < 2; ++kk) {
        bf16x8 bkh = *(const bf16x8*)&Kh[(j * 16 + l15) * AP + kk * 32 + quad * 8];
        bf16x8 bkl = *(const bf16x8*)&Kl[(j * 16 + l15) * AP + kk * 32 + quad * 8];
        sc[j] = __builtin_amdgcn_mfma_f32_16x16x32_bf16(aqh[kk], bkh, sc[j], 0, 0, 0);
        sc[j] = __builtin_amdgcn_mfma_f32_16x16x32_bf16(aqh[kk], bkl, sc[j], 0, 0, 0);
        sc[j] = __builtin_amdgcn_mfma_f32_16x16x32_bf16(aql[kk], bkh, sc[j], 0, 0, 0);
      }
    }
    float ds_[4];
    #pragma unroll
    for (int j = 0; j < 4; ++j) ds_[j] = sds[j * 16 + l15];
    float s_[4][4];
    #pragma unroll
    for (int j = 0; j < 4; ++j)
      #pragma unroll
      for (int i = 0; i < 4; ++i)
        s_[j][i] = sc[j][i] * 0.125f - sp * fabsf(dq[i] - ds_[j]);
    float mx[4];
    #pragma unroll
    for (int i = 0; i < 4; ++i)
      mx[i] = fmaxf(fmaxf(s_[0][i], s_[1][i]), fmaxf(s_[2][i], s_[3][i]));
    #pragma unroll
    for (int d = 1; d < 16; d <<= 1)
      #pragma unroll
      for (int i = 0; i < 4; ++i) mx[i] = fmaxf(mx[i], __shfl_xor(mx[i], d));
    float al[4], rsum[4], p[4][4];
    #pragma unroll
    for (int i = 0; i < 4; ++i) {
      float mn = fmaxf(mr[i], mx[i]);
      al[i] = __expf(mr[i] - mn);
      mr[i] = mn;
      rsum[i] = 0.f;
      #pragma unroll
      for (int j = 0; j < 4; ++j) { p[j][i] = __expf(s_[j][i] - mn); rsum[i] += p[j][i]; }
    }
    #pragma unroll
    for (int d = 1; d < 16; d <<= 1)
      #pragma unroll
      for (int i = 0; i < 4; ++i) rsum[i] += __shfl_xor(rsum[i], d);
    #pragma unroll
    for (int i = 0; i < 4; ++i) {
      lr[i] = lr[i] * al[i] + rsum[i];
      #pragma unroll
      for (int j = 0; j < 4; ++j) oa[j][i] *= al[i];
    }
    #pragma unroll
    for (int j = 0; j < 4; ++j)
      #pragma unroll
      for (int i = 0; i < 4; ++i) {
        float pv = p[j][i];
        u16 hv = f2b(pv);
        Ph[w][(quad * 4 + i) * AP + j * 16 + l15] = hv;
        Pl[w][(quad * 4 + i) * AP + j * 16 + l15] = f2b(pv - b2f(hv));
      }
    bf16x8 aph[2], apl[2];
    #pragma unroll
    for (int kk = 0; kk < 2; ++kk) {
      aph[kk] = *(const bf16x8*)&Ph[w][l15 * AP + kk * 32 + quad * 8];
      apl[kk] = *(const bf16x8*)&Pl[w][l15 * AP + kk * 32 + quad * 8];
    }
    #pragma unroll
    for (int j = 0; j < 4; ++j) {
      #pragma unroll
      for (int kk = 0; kk < 2; ++kk) {
        bf16x8 bvh = *(const bf16x8*)&Vth[(j * 16 + l15) * AP + kk * 32 + quad * 8];
        bf16x8 bvl = *(const bf16x8*)&Vtl[(j * 16 + l15) * AP + kk * 32 + quad * 8];
        oa[j] = __builtin_amdgcn_mfma_f32_16x16x32_bf16(aph[kk], bvh, oa[j], 0, 0, 0);
        oa[j] = __builtin_amdgcn_mfma_f32_16x16x32_bf16(aph[kk], bvl, oa[j], 0, 0, 0);
        oa[j] = __builtin_amdgcn_mfma_f32_16x16x32_bf16(apl[kk], bvh, oa[j], 0, 0, 0);
      }
    }
  }
  #pragma unroll
  for (int i = 0; i < 4; ++i) {
    float inv = 1.f / lr[i];
    int q = b * S_ + q0 + w * 16 + quad * 4 + i;
    #pragma unroll
    for (int j = 0; j < 4; ++j) {
      float ov = oa[j][i] * inv;
      size_t idx = (size_t)q * (H_ * HD_) + h * HD_ + j * 16 + l15;
      u16 hv = f2b(ov);
      o_h[idx] = hv;
      o_l[idx] = f2b(ov - b2f(hv));
    }
  }
}

// ---------------- router ----------------
__global__ __launch_bounds__(256) void k_router(const float* __restrict__ xn2,
                                                const float* __restrict__ rw,
                                                const float* __restrict__ rb,
                                                int* __restrict__ eidx, int* __restrict__ epos,
                                                float* __restrict__ ew, int* __restrict__ cnt,
                                                int* __restrict__ list) {
  int t = blockIdx.x * 4 + (threadIdx.x >> 6);
  int l = threadIdx.x & 63;
  const float* row = xn2 + (size_t)t * D_;
  float acc[8];
  #pragma unroll
  for (int e = 0; e < 8; ++e) acc[e] = 0.f;
  for (int i = 0; i < 16; ++i) {
    int d = l + i * 64;
    float xv = row[d];
    float4 w0 = *(const float4*)&rw[d * 8 + 0];
    float4 w1 = *(const float4*)&rw[d * 8 + 4];
    acc[0] = fmaf(xv, w0.x, acc[0]); acc[1] = fmaf(xv, w0.y, acc[1]);
    acc[2] = fmaf(xv, w0.z, acc[2]); acc[3] = fmaf(xv, w0.w, acc[3]);
    acc[4] = fmaf(xv, w1.x, acc[4]); acc[5] = fmaf(xv, w1.y, acc[5]);
    acc[6] = fmaf(xv, w1.z, acc[6]); acc[7] = fmaf(xv, w1.w, acc[7]);
  }
  #pragma unroll
  for (int off = 32; off > 0; off >>= 1)
    #pragma unroll
    for (int e = 0; e < 8; ++e) acc[e] += __shfl_xor(acc[e], off);
  if (l == 0) {
    float lg[8];
    #pragma unroll
    for (int e = 0; e < 8; ++e) lg[e] = acc[e] + rb[e];
    int i1 = 0;
    #pragma unroll
    for (int e = 1; e < 8; ++e) if (lg[e] > lg[i1]) i1 = e;
    int i2 = (i1 == 0) ? 1 : 0;
    #pragma unroll
    for (int e = 0; e < 8; ++e) if (e != i1 && lg[e] > lg[i2]) i2 = e;
    float wa = 1.f / (1.f + __expf(lg[i2] - lg[i1]));
    float wb = 1.f - wa;
    int pa = atomicAdd(&cnt[i1], 1);
    int pb = atomicAdd(&cnt[i2], 1);
    list[i1 * T_ + pa] = t;
    list[i2 * T_ + pb] = t;
    eidx[2 * t] = i1; eidx[2 * t + 1] = i2;
    epos[2 * t] = pa; epos[2 * t + 1] = pb;
    ew[2 * t] = wa; ew[2 * t + 1] = wb;
  }
}

__global__ void k_offsets(const int* __restrict__ cnt, int* __restrict__ offs) {
  if (threadIdx.x == 0 && blockIdx.x == 0) {
    int tot = 0;
    for (int e = 0; e < E_; ++e) { offs[e] = tot; tot += cnt[e]; }
  }
}

// ---------------- bf16 MFMA GEMM for MoE (double-buffered LDS) ----------------
// MODE 0: h[slot] = gelu(xn2b[list] @ w1t[e]^T + b1[e]) -> u16
// MODE 1: y[slot] = h[slot] @ w2t[e]^T + b2[e]          -> u16
template <int MODE>
__global__ __launch_bounds__(256) void k_moe_gemm(const u16* __restrict__ Ab,
                                                  const u16* __restrict__ Wt,
                                                  const float* __restrict__ bias,
                                                  u16* __restrict__ outU,
                                                  const int* __restrict__ cnt,
                                                  const int* __restrict__ offs,
                                                  const int* __restrict__ list,
                                                  int N, int K) {
  int e = blockIdx.z;
  int myM = cnt[e];
  int m0 = blockIdx.x * 128;
  if (m0 >= myM) return;
  int n0 = blockIdx.y * 128;
  __shared__ __align__(16) u16 As[2][128 * 32];
  __shared__ __align__(16) u16 Bs[2][128 * 32];
  int tid = threadIdx.x, w = tid >> 6, l = tid & 63;
  int quad = l >> 4, l15 = l & 15;
  int koff = (l & 3) * 8;
  const u16* ap[2];
  const u16* bp[2];
  #pragma unroll
  for (int c = 0; c < 2; ++c) {
    int chunk = c * 4 + w;
    int r = m0 + chunk * 16 + (l >> 2);
    int rr = (r < myM) ? r : (myM - 1);
    if (MODE == 0) {
      int tok = list[e * T_ + rr];
      ap[c] = Ab + (size_t)tok * K + koff;
    } else {
      ap[c] = Ab + (size_t)(offs[e] + rr) * K + koff;
    }
    int nrow = n0 + chunk * 16 + (l >> 2);
    bp[c] = Wt + (size_t)e * N * K + (size_t)nrow * K + koff;
  }
  f32x4 acc[4][4] = {};
  int wm = (w & 1) * 64, wn = (w >> 1) * 64;
  int nsteps = K >> 5;
  // prologue: stage 0
  #pragma unroll
  for (int c = 0; c < 2; ++c) {
    gload16(ap[c], &As[0][(c * 4 + w) * 512]);
    gload16(bp[c], &Bs[0][(c * 4 + w) * 512]);
  }
  __syncthreads();
  for (int it = 0; it < nsteps; ++it) {
    int cur = it & 1;
    if (it + 1 < nsteps) {
      int k0 = (it + 1) << 5;
      #pragma unroll
      for (int c = 0; c < 2; ++c) {
        gload16(ap[c] + k0, &As[cur ^ 1][(c * 4 + w) * 512]);
        gload16(bp[c] + k0, &Bs[cur ^ 1][(c * 4 + w) * 512]);
      }
    }
    bf16x8 af[4], bfv[4];
    #pragma unroll
    for (int i = 0; i < 4; ++i)
      af[i] = *(const bf16x8*)&As[cur][(wm + i * 16 + l15) * 32 + quad * 8];
    #pragma unroll
    for (int j = 0; j < 4; ++j)
      bfv[j] = *(const bf16x8*)&Bs[cur][(wn + j * 16 + l15) * 32 + quad * 8];
    #pragma unroll
    for (int i = 0; i < 4; ++i)
      #pragma unroll
      for (int j = 0; j < 4; ++j)
        acc[i][j] = __builtin_amdgcn_mfma_f32_16x16x32_bf16(af[i], bfv[j], acc[i][j], 0, 0, 0);
    __syncthreads();  // prefetch landed + all ds_reads of cur done
  }
  const float* bptr = bias + (size_t)e * N;
  #pragma unroll
  for (int i = 0; i < 4; ++i) {
    #pragma unroll
    for (int j = 0; j < 4; ++j) {
      int gn = n0 + wn + j * 16 + l15;
      float bv = bptr[gn];
      #pragma unroll
      for (int r = 0; r < 4; ++r) {
        int gm = m0 + wm + i * 16 + quad * 4 + r;
        if (gm < myM) {
          float vv = acc[i][j][r] + bv;
          if (MODE == 0) vv = gelu_t(vv);
          outU[(size_t)(offs[e] + gm) * N + gn] = f2b(vv);
        }
      }
    }
  }
}

// ---------------- final combine ----------------
__global__ __launch_bounds__(256) void k_combine(const float* __restrict__ x1,
                                                 const u16* __restrict__ y,
                                                 const int* __restrict__ eidx,
                                                 const int* __restrict__ epos,
                                                 const float* __restrict__ ew,
                                                 const int* __restrict__ offs,
                                                 float* __restrict__ out) {
  int t = blockIdx.x, tid = threadIdx.x;
  int e0 = eidx[2 * t], e1 = eidx[2 * t + 1];
  int s0 = offs[e0] + epos[2 * t];
  int s1 = offs[e1] + epos[2 * t + 1];
  float w0 = ew[2 * t], w1 = ew[2 * t + 1];
  int d = tid * 4;
  float4 a = *(const float4*)&x1[(size_t)t * D_ + d];
  ushort4 y0 = *(const ushort4*)&y[(size_t)s0 * D_ + d];
  ushort4 y1 = *(const ushort4*)&y[(size_t)s1 * D_ + d];
  float4 r;
  r.x = a.x + w0 * b2f(y0.x) + w1 * b2f(y1.x);
  r.y = a.y + w0 * b2f(y0.y) + w1 * b2f(y1.y);
  r.z = a.z + w0 * b2f(y0.z) + w1 * b2f(y1.z);
  r.w = a.w + w0 * b2f(y0.w) + w1 * b2f(y1.w);
  *(float4*)&out[(size_t)t * D_ + d] = r;
}

// ---------------- launch ----------------
extern "C" void kernel_launch(void* const* d_in, const int* in_sizes, int n_in,
                              void* d_out, int out_size, void* d_ws, size_t ws_size,
                              hipStream_t stream) {
  (void)in_sizes; (void)n_in; (void)out_size; (void)ws_size;
  const float* x    = (const float*)d_in[0];
  const float* sd   = (const float*)d_in[1];
  const float* ln1s = (const float*)d_in[2];
  const float* ln1b = (const float*)d_in[3];
  const float* wq   = (const float*)d_in[4];
  const float* bq   = (const float*)d_in[5];
  const float* wk   = (const float*)d_in[6];
  const float* bk   = (const float*)d_in[7];
  const float* wv   = (const float*)d_in[8];
  const float* bv   = (const float*)d_in[9];
  const float* wo   = (const float*)d_in[10];
  const float* bo   = (const float*)d_in[11];
  const float* td   = (const float*)d_in[12];
  const float* ln2s = (const float*)d_in[13];
  const float* ln2b = (const float*)d_in[14];
  const float* rw   = (const float*)d_in[15];
  const float* rb   = (const float*)d_in[16];
  const float* w1   = (const float*)d_in[17];
  const float* b1   = (const float*)d_in[18];
  const float* w2   = (const float*)d_in[19];
  const float* b2   = (const float*)d_in[20];
  float* out = (float*)d_out;

  const size_t MBy = 1024ull * 1024ull;
  char* ws = (char*)d_ws;
  u16*   w1t   = (u16*)(ws + 0);          // 64MB   [prep -> moe1]
  u16*   w2t   = (u16*)(ws + 64 * MBy);   // 64MB   [prep -> moe2]
  u16*   hb    = (u16*)(ws + 128 * MBy);  // 64MB   [moe1 -> moe2]
  float* xn2   = (float*)(ws + 128 * MBy);// 16MB   aliases hb (dead before moe1)
  u16*   wqkvTh= (u16*)(ws + 192 * MBy);  // 3MB
  u16*   wqkvTl= (u16*)(ws + 195 * MBy);  // 3MB
  u16*   woTh  = (u16*)(ws + 198 * MBy);  // 2MB
  u16*   woTl  = (u16*)(ws + 200 * MBy);  // 2MB
  float* bqkv  = (float*)(ws + 202 * MBy);// 6KB
  int*   eidx  = (int*)(ws + 202 * MBy + 65536);
  int*   epos  = eidx + 2 * T_;
  float* ew    = (float*)(epos + 2 * T_);
  int*   list  = (int*)(ew + 2 * T_);
  int*   cnt   = list + E_ * T_;
  int*   offs  = cnt + E_;
  u16*   xn_h  = (u16*)(ws + 203 * MBy);  // 8MB    [ln1 -> qkv gemm]
  u16*   xn_l  = (u16*)(ws + 211 * MBy);  // 8MB
  u16*   xn2b  = (u16*)(ws + 203 * MBy);  // 8MB    aliases xn_h (dead)
  u16*   qkv_h = (u16*)(ws + 219 * MBy);  // 13MB   [qkv -> attn]
  u16*   qkv_l = (u16*)(ws + 232 * MBy);  // 13MB
  u16*   yb    = (u16*)(ws + 219 * MBy);  // 16MB   aliases qkv (dead after attn)
  u16*   o_h   = (u16*)(ws + 245 * MBy);  // 8MB    [attn -> outproj]
  u16*   o_l   = (u16*)(ws + 253 * MBy);  // 8MB
  float* x1    = (float*)(ws + 261 * MBy);// 16MB   [outproj -> combine]

  k_zero<<<1, 64, 0, stream>>>(cnt);
  k_transpose<<<dim3(F_ / 32, D_ / 32, E_), dim3(32, 8), 0, stream>>>(w1, w1t, D_, F_);
  k_transpose<<<dim3(D_ / 32, F_ / 32, E_), dim3(32, 8), 0, stream>>>(w2, w2t, F_, D_);
  k_split_transpose<<<dim3(1024 / 32, 1024 / 32), dim3(32, 8), 0, stream>>>(wq, wqkvTh, wqkvTl, 1024, 1024);
  k_split_transpose<<<dim3(256 / 32, 1024 / 32), dim3(32, 8), 0, stream>>>(wk, wqkvTh + 1024 * 1024, wqkvTl + 1024 * 1024, 1024, 256);
  k_split_transpose<<<dim3(256 / 32, 1024 / 32), dim3(32, 8), 0, stream>>>(wv, wqkvTh + 1280 * 1024, wqkvTl + 1280 * 1024, 1024, 256);
  k_split_transpose<<<dim3(1024 / 32, 1024 / 32), dim3(32, 8), 0, stream>>>(wo, woTh, woTl, 1024, 1024);
  k_prep_bias<<<6, 256, 0, stream>>>(bq, bk, bv, bqkv);

  k_ln<<<T_, 256, 0, stream>>>(x, ln1s, ln1b, nullptr, nullptr, xn_h, xn_l);

  k_gemm_split<0><<<dim3(T_ / 128, 1536 / 128), 256, 0, stream>>>(
      xn_h, xn_l, wqkvTh, wqkvTl, bqkv, nullptr, qkv_h, qkv_l, nullptr, T_, 1536, 1024);

  k_attn_mfma<<<dim3(S_ / 64, H_, B_), 256, 0, stream>>>(qkv_h, qkv_l, sd, td, o_h, o_l);

  k_gemm_split<1><<<dim3(T_ / 128, 1024 / 128), 256, 0, stream>>>(
      o_h, o_l, woTh, woTl, bo, x, nullptr, nullptr, x1, T_, 1024, 1024);

  k_ln<<<T_, 256, 0, stream>>>(x1, ln2s, ln2b, xn2, xn2b, nullptr, nullptr);

  k_router<<<T_ / 4, 256, 0, stream>>>(xn2, rw, rb, eidx, epos, ew, cnt, list);
  k_offsets<<<1, 64, 0, stream>>>(cnt, offs);

  k_moe_gemm<0><<<dim3(32, F_ / 128, E_), 256, 0, stream>>>(xn2b, w1t, b1, hb, cnt, offs, list, F_, D_);
  k_moe_gemm<1><<<dim3(32, D_ / 128, E_), 256, 0, stream>>>(hb, w2t, b2, yb, cnt, offs, list, D_, F_);

  k_combine<<<T_, 256, 0, stream>>>(x1, yb, eidx, epos, ew, offs, out);
}